// Round 4
// baseline (1533.690 us; speedup 1.0000x reference)
//
#include <hip/hip_runtime.h>
#include <hip/hip_bf16.h>
#include <cstdint>
#include <cstddef>

// Shapes: B=64, T=512, J=64, D=256, E=128, gdim=8E=1024, gates=4E=512
// ws layout (bytes), total 134,742,016 (~128.5 MiB):
//   [0,           67,108,864)  g as bf16 (32768 x 1024)   -- dead after gemm1
//        aliased: m  bf16 (32768 x 256) at offset 0
//                 m2 bf16 (32768 x 256) at offset 33,554,432
//   [67,108,864, 100,663,296)  pre_f bf16 (32768 x 512)
//   [100,663,296,134,217,728)  pre_b bf16 (32768 x 512)
//   [134,217,728,...]          gz0, gz1, smax, z  (32768 fp32 each)

typedef short short8v __attribute__((ext_vector_type(8)));
typedef float f32x4 __attribute__((ext_vector_type(4)));
typedef unsigned short ushort8v __attribute__((ext_vector_type(8)));

static __device__ __forceinline__ float bf2f(unsigned short u) {
  return __uint_as_float(((unsigned int)u) << 16);
}
static __device__ __forceinline__ unsigned short f2bf(float f) {  // RNE
  unsigned int u = __float_as_uint(f);
  return (unsigned short)((u + 0x7FFFu + ((u >> 16) & 1u)) >> 16);
}
static __device__ __forceinline__ float fsig(float x) {
  return 1.f / (1.f + __expf(-x));
}
static __device__ __forceinline__ float ftanh(float x) {
  return 1.f - 2.f / (__expf(2.f * x) + 1.f);
}

// ---------------- attention: s, softmax_j, c2q, smax, g[0:768] bf16, gz partial ----
// grid (64, 4)  block 256.  LDS ~133KB -> 1 block/CU.
__global__ __launch_bounds__(256) void attn_kernel(
    const float* __restrict__ c, const float* __restrict__ q,
    const float* __restrict__ wc, const float* __restrict__ bc,
    const float* __restrict__ wq, const float* __restrict__ bq,
    const float* __restrict__ wcq, const float* __restrict__ bcq,
    const float* __restrict__ W0, const float* __restrict__ W1,
    __hip_bfloat16* __restrict__ g, float* __restrict__ smax,
    float* __restrict__ gz0, float* __restrict__ gz1)
{
  __shared__ float qr[64][256];    // j-major (c2q: lanes sweep d, conflict-free)
  __shared__ float qrt[256][64];   // d-major (s-dot: lanes sweep j, conflict-free)
  __shared__ float qwqs[64];
  __shared__ float cwbuf[4][256];  // per-wave c*wcq row (wave-private)
  __shared__ float abuf[4][64];    // per-wave attention weights (wave-private)
  const int b = blockIdx.x;
  const int tid = threadIdx.x;
  for (int e = tid; e < 64 * 256; e += 256) {
    int j = e >> 8, d = e & 255;
    float v = q[((size_t)b * 64 + j) * 256 + d];
    qr[j][d] = v;
    qrt[d][j] = v;
  }
  __syncthreads();
  if (tid < 64) {
    float s = 0.f;
    for (int d = 0; d < 256; ++d) s += qrt[d][tid] * wq[d];
    qwqs[tid] = s + bq[0];
  }
  __syncthreads();
  const int wave = tid >> 6, lane = tid & 63;
  const float bcv = bc[0], bcqv = bcq[0];
  const int t0 = blockIdx.y * 128;
  for (int it = 0; it < 32; ++it) {
    const int trow = t0 + wave + it * 4;
    const float* crow = c + ((size_t)b * 512 + trow) * 256;
    float cv[4];
    float part = 0.f;
    #pragma unroll
    for (int r = 0; r < 4; ++r) {
      int d = lane + 64 * r;
      cv[r] = crow[d];
      cwbuf[wave][d] = cv[r] * wcq[d];
      part += cv[r] * wc[d];
    }
    #pragma unroll
    for (int off = 32; off; off >>= 1) part += __shfl_xor(part, off);
    float s = part + bcv + qwqs[lane] + bcqv;   // lane == j
    #pragma unroll 8
    for (int d = 0; d < 256; ++d) s += cwbuf[wave][d] * qrt[d][lane];
    float mx = s;
    #pragma unroll
    for (int off = 32; off; off >>= 1) mx = fmaxf(mx, __shfl_xor(mx, off));
    float e = expf(s - mx);
    float sum = e;
    #pragma unroll
    for (int off = 32; off; off >>= 1) sum += __shfl_xor(sum, off);
    abuf[wave][lane] = e / sum;
    const size_t grow = (size_t)b * 512 + trow;
    if (lane == 0) smax[grow] = mx;
    size_t row = grow * 1024;
    float az0 = 0.f, az1 = 0.f;
    #pragma unroll
    for (int r = 0; r < 4; ++r) {
      int d = lane + 64 * r;
      float acc = 0.f;
      #pragma unroll 8
      for (int j = 0; j < 64; ++j) acc += abuf[wave][j] * qr[j][d];
      float prod = cv[r] * acc;
      g[row + d]       = __float2bfloat16(cv[r]);
      g[row + 256 + d] = __float2bfloat16(acc);
      g[row + 512 + d] = __float2bfloat16(prod);
      az0 += cv[r] * W0[d] + acc * W0[256 + d] + prod * W0[512 + d];
      az1 += cv[r] * W1[d] + acc * W1[256 + d] + prod * W1[512 + d];
    }
    #pragma unroll
    for (int off = 32; off; off >>= 1) {
      az0 += __shfl_xor(az0, off);
      az1 += __shfl_xor(az1, off);
    }
    if (lane == 0) { gz0[grow] = az0; gz1[grow] = az1; }
  }
}

// ---------------- b_att softmax over t, q2c, g[768:1024] bf16, gz tail ----------
// grid 64, block 256
__global__ __launch_bounds__(256) void batt_kernel(
    const float* __restrict__ c, const float* __restrict__ smax,
    const float* __restrict__ W0, const float* __restrict__ W1,
    __hip_bfloat16* __restrict__ g,
    float* __restrict__ gz0, float* __restrict__ gz1)
{
  __shared__ float sm[512];
  __shared__ float red[4], red2[4];
  __shared__ float q2c_s[256];
  const int b = blockIdx.x, tid = threadIdx.x;
  float v0 = smax[(size_t)b * 512 + tid];
  float v1 = smax[(size_t)b * 512 + tid + 256];
  float m = fmaxf(v0, v1);
  #pragma unroll
  for (int off = 32; off; off >>= 1) m = fmaxf(m, __shfl_xor(m, off));
  if ((tid & 63) == 0) red[tid >> 6] = m;
  __syncthreads();
  float M = fmaxf(fmaxf(red[0], red[1]), fmaxf(red[2], red[3]));
  float e0 = expf(v0 - M), e1 = expf(v1 - M);
  float ssum = e0 + e1;
  #pragma unroll
  for (int off = 32; off; off >>= 1) ssum += __shfl_xor(ssum, off);
  if ((tid & 63) == 0) red2[tid >> 6] = ssum;
  __syncthreads();
  float S = red2[0] + red2[1] + red2[2] + red2[3];
  sm[tid] = e0 / S;
  sm[tid + 256] = e1 / S;
  __syncthreads();
  float acc = 0.f;
  #pragma unroll 8
  for (int t = 0; t < 512; ++t) acc += sm[t] * c[((size_t)b * 512 + t) * 256 + tid];
  q2c_s[tid] = acc;
  __syncthreads();
  const int wave = tid >> 6, lane = tid & 63;
  float qv[4], w0c[4], w1c[4];
  #pragma unroll
  for (int r = 0; r < 4; ++r) {
    int d = lane + 64 * r;
    qv[r]  = q2c_s[d];
    w0c[r] = W0[768 + d];
    w1c[r] = W1[768 + d];
  }
  for (int t = wave; t < 512; t += 4) {
    size_t row = (size_t)b * 512 + t;
    float s0 = 0.f, s1 = 0.f;
    #pragma unroll
    for (int r = 0; r < 4; ++r) {
      int d = lane + 64 * r;
      float v = c[row * 256 + d];
      float gv = v * qv[r];
      g[row * 1024 + 768 + d] = __float2bfloat16(gv);
      s0 += gv * w0c[r];
      s1 += gv * w1c[r];
    }
    #pragma unroll
    for (int off = 32; off; off >>= 1) {
      s0 += __shfl_xor(s0, off);
      s1 += __shfl_xor(s1, off);
    }
    if (lane == 0) { gz0[row] += s0; gz1[row] += s1; }
  }
}

// ---------------- MFMA GEMM: Ybf16[M,N] = Xbf16[M,K] @ Wfp32[N,K]^T + b1 + b2 ---
// grid (M/128, N/128), block 256 (4 waves, each 64x64). BK=64. W cvt'd inline.
__global__ __launch_bounds__(256) void gemm_mfma_kernel(
    const __hip_bfloat16* __restrict__ Xg, const float* __restrict__ W,
    const float* __restrict__ bias1, const float* __restrict__ bias2,
    __hip_bfloat16* __restrict__ Y, int K, int N)
{
  __shared__ unsigned short Xs[128 * 72];  // row stride 72 (+8 pad = 16B, b128-aligned)
  __shared__ unsigned short Ws[128 * 72];
  const unsigned short* X = (const unsigned short*)Xg;
  const int tid = threadIdx.x;
  const int m0 = blockIdx.x * 128, n0 = blockIdx.y * 128;
  const int lane = tid & 63, wave = tid >> 6;
  const int wr = wave >> 1, wc = wave & 1;
  const int frow = lane & 15, fk = (lane >> 4) * 8;

  f32x4 acc[4][4] = {};
  for (int kt = 0; kt < K; kt += 64) {
    #pragma unroll
    for (int i = 0; i < 4; ++i) {
      int cidx = tid + 256 * i;          // 0..1023
      int row = cidx >> 3, kc = cidx & 7;
      ushort8v v = *(const ushort8v*)&X[(size_t)(m0 + row) * K + kt + kc * 8];
      *(ushort8v*)&Xs[row * 72 + kc * 8] = v;
    }
    #pragma unroll
    for (int i = 0; i < 4; ++i) {
      int cidx = tid + 256 * i;
      int row = cidx >> 3, kc = cidx & 7;
      const float* wp = &W[(size_t)(n0 + row) * K + kt + kc * 8];
      float4 f0 = *(const float4*)wp;
      float4 f1 = *(const float4*)(wp + 4);
      ushort8v v;
      v[0] = f2bf(f0.x); v[1] = f2bf(f0.y); v[2] = f2bf(f0.z); v[3] = f2bf(f0.w);
      v[4] = f2bf(f1.x); v[5] = f2bf(f1.y); v[6] = f2bf(f1.z); v[7] = f2bf(f1.w);
      *(ushort8v*)&Ws[row * 72 + kc * 8] = v;
    }
    __syncthreads();
    #pragma unroll
    for (int kk = 0; kk < 64; kk += 32) {
      short8v a[4], bfr[4];
      #pragma unroll
      for (int i = 0; i < 4; ++i)
        a[i] = *(const short8v*)&Xs[(wr * 64 + i * 16 + frow) * 72 + kk + fk];
      #pragma unroll
      for (int j = 0; j < 4; ++j)
        bfr[j] = *(const short8v*)&Ws[(wc * 64 + j * 16 + frow) * 72 + kk + fk];
      #pragma unroll
      for (int i = 0; i < 4; ++i)
        #pragma unroll
        for (int j = 0; j < 4; ++j)
          acc[i][j] = __builtin_amdgcn_mfma_f32_16x16x32_bf16(a[i], bfr[j], acc[i][j], 0, 0, 0);
    }
    __syncthreads();
  }
  const int r0 = (lane >> 4) * 4;
  #pragma unroll
  for (int j = 0; j < 4; ++j) {
    int col = n0 + wc * 64 + j * 16 + (lane & 15);
    float bsum = bias1[col] + bias2[col];
    #pragma unroll
    for (int i = 0; i < 4; ++i) {
      int rowb = m0 + wr * 64 + i * 16 + r0;
      #pragma unroll
      for (int r = 0; r < 4; ++r)
        Y[(size_t)(rowb + r) * N + col] = __float2bfloat16(acc[i][j][r] + bsum);
    }
  }
}

// ---------------- LSTM recurrence (wave-local gates, 1 barrier/step) ----------
// grid (64, 2) block 512, __launch_bounds__(512,2) so w[128] stays in VGPRs.
// wave w, lane l: cell j = w*16+(l&15), gate q = l>>4, row = q*128+j.
// h double-buffered in LDS; gates gathered via 4 in-wave shuffles.
__global__ __launch_bounds__(512, 2) void lstm_kernel(
    const __hip_bfloat16* __restrict__ pre_f, const __hip_bfloat16* __restrict__ pre_b,
    const float* __restrict__ Whh_f, const float* __restrict__ Whh_b,
    __hip_bfloat16* __restrict__ out)
{
  const int b = blockIdx.x, dir = blockIdx.y;
  const unsigned short* __restrict__ pre =
      (const unsigned short*)(dir ? pre_b : pre_f);
  const float* __restrict__ Whh = dir ? Whh_b : Whh_f;
  const int off = dir ? 128 : 0;
  const int tid = threadIdx.x;
  const int wave = tid >> 6, lane = tid & 63;
  const int q = lane >> 4;                  // 0=i 1=f 2=g 3=o
  const int j = wave * 16 + (lane & 15);    // cell 0..127
  const int row = q * 128 + j;              // gate row 0..511
  float w[128];
  #pragma unroll
  for (int k4 = 0; k4 < 32; ++k4)
    *(float4*)&w[k4 * 4] = *(const float4*)&Whh[(size_t)row * 128 + k4 * 4];
  __shared__ float hbuf[2][128];
  if (tid < 128) { hbuf[0][tid] = 0.f; hbuf[1][tid] = 0.f; }
  float cst = 0.f;
  __syncthreads();
  const size_t base = (size_t)b * 512;
  int t = dir ? 511 : 0;
  const int tstep = dir ? -1 : 1;
  float pcur = bf2f(pre[(base + t) * 512 + row]);
  int cur = 0;
  const int l0 = lane & 15;
  for (int s = 0; s < 512; ++s) {
    float pnext = 0.f;
    if (s < 511) pnext = bf2f(pre[(base + t + tstep) * 512 + row]);
    const float* h = hbuf[cur];
    float a0 = pcur, a1 = 0.f, a2 = 0.f, a3 = 0.f;
    #pragma unroll
    for (int k4 = 0; k4 < 32; ++k4) {
      float4 hv = *(const float4*)&h[k4 * 4];
      a0 += w[k4 * 4 + 0] * hv.x; a1 += w[k4 * 4 + 1] * hv.y;
      a2 += w[k4 * 4 + 2] * hv.z; a3 += w[k4 * 4 + 3] * hv.w;
    }
    float preact = (a0 + a1) + (a2 + a3);
    float a = (q == 2) ? ftanh(preact) : fsig(preact);
    float gi_ = __shfl(a, l0);
    float gf_ = __shfl(a, l0 + 16);
    float gg_ = __shfl(a, l0 + 32);
    float go_ = __shfl(a, l0 + 48);
    cst = gf_ * cst + gi_ * gg_;             // replicated across the 4 lane groups
    float hv = go_ * ftanh(cst);
    if (q == 0) {
      hbuf[cur ^ 1][j] = hv;
      out[(base + t) * 256 + off + j] = __float2bfloat16(hv);
    }
    __syncthreads();
    pcur = pnext;
    t += tstep;
    cur ^= 1;
  }
}

// ---------------- logits: z[row] = gz[row] + m_row(bf16) . W[1024:1280] + bias ----
// grid 8192, block 256 (wave per row)
__global__ __launch_bounds__(256) void logits_kernel(
    const __hip_bfloat16* __restrict__ m, const float* __restrict__ W,
    const float* __restrict__ bias, const float* __restrict__ gz,
    float* __restrict__ z)
{
  const int row = blockIdx.x * 4 + (threadIdx.x >> 6);
  const int lane = threadIdx.x & 63;
  const unsigned short* mrow = (const unsigned short*)m + (size_t)row * 256;
  float acc = 0.f;
  #pragma unroll
  for (int i = 0; i < 4; ++i) acc += bf2f(mrow[lane + 64 * i]) * W[1024 + lane + 64 * i];
  #pragma unroll
  for (int off = 32; off; off >>= 1) acc += __shfl_xor(acc, off);
  if (lane == 0) z[row] = acc + gz[row] + bias[0];
}

// ---------------- softmax over t ----------------
// grid 64, block 512
__global__ __launch_bounds__(512) void softmax_t_kernel(
    const float* __restrict__ z, float* __restrict__ p)
{
  const int b = blockIdx.x, t = threadIdx.x;
  __shared__ float red[8], red2[8];
  float v = z[(size_t)b * 512 + t];
  float m = v;
  #pragma unroll
  for (int off = 32; off; off >>= 1) m = fmaxf(m, __shfl_xor(m, off));
  if ((t & 63) == 0) red[t >> 6] = m;
  __syncthreads();
  float M = red[0];
  #pragma unroll
  for (int i = 1; i < 8; ++i) M = fmaxf(M, red[i]);
  float e = expf(v - M);
  float s = e;
  #pragma unroll
  for (int off = 32; off; off >>= 1) s += __shfl_xor(s, off);
  if ((t & 63) == 0) red2[t >> 6] = s;
  __syncthreads();
  float S = red2[0];
  #pragma unroll
  for (int i = 1; i < 8; ++i) S += red2[i];
  p[(size_t)b * 512 + t] = e / S;
}

extern "C" void kernel_launch(void* const* d_in, const int* in_sizes, int n_in,
                              void* d_out, int out_size, void* d_ws, size_t ws_size,
                              hipStream_t stream)
{
  const float* c   = (const float*)d_in[0];
  const float* q   = (const float*)d_in[1];
  const float* wc  = (const float*)d_in[2];
  const float* bc  = (const float*)d_in[3];
  const float* wq  = (const float*)d_in[4];
  const float* bq  = (const float*)d_in[5];
  const float* wcq = (const float*)d_in[6];
  const float* bcq = (const float*)d_in[7];
  const float* l1f_Wih = (const float*)d_in[8];
  const float* l1f_Whh = (const float*)d_in[9];
  const float* l1f_bih = (const float*)d_in[10];
  const float* l1f_bhh = (const float*)d_in[11];
  const float* l1b_Wih = (const float*)d_in[12];
  const float* l1b_Whh = (const float*)d_in[13];
  const float* l1b_bih = (const float*)d_in[14];
  const float* l1b_bhh = (const float*)d_in[15];
  const float* l2f_Wih = (const float*)d_in[16];
  const float* l2f_Whh = (const float*)d_in[17];
  const float* l2f_bih = (const float*)d_in[18];
  const float* l2f_bhh = (const float*)d_in[19];
  const float* l2b_Wih = (const float*)d_in[20];
  const float* l2b_Whh = (const float*)d_in[21];
  const float* l2b_bih = (const float*)d_in[22];
  const float* l2b_bhh = (const float*)d_in[23];
  const float* W0 = (const float*)d_in[24];
  const float* b0 = (const float*)d_in[25];
  const float* W1 = (const float*)d_in[26];
  const float* b1 = (const float*)d_in[27];

  const size_t required = 134742016u;
  if (ws_size < required) return;

  char* wsb = (char*)d_ws;
  __hip_bfloat16* gbf = (__hip_bfloat16*)wsb;                  // 67,108,864 B
  __hip_bfloat16* m   = (__hip_bfloat16*)wsb;                  // alias (g dead after gemm1)
  __hip_bfloat16* m2  = (__hip_bfloat16*)(wsb + 33554432);     // alias
  __hip_bfloat16* pref = (__hip_bfloat16*)(wsb + 67108864);    // 33,554,432 B
  __hip_bfloat16* preb = (__hip_bfloat16*)(wsb + 100663296);   // 33,554,432 B
  float* gz0  = (float*)(wsb + 134217728);
  float* gz1  = gz0 + 32768;
  float* smax = gz1 + 32768;
  float* z    = smax + 32768;
  float* p1   = (float*)d_out;
  float* p2   = p1 + 32768;

  attn_kernel<<<dim3(64, 4), 256, 0, stream>>>(c, q, wc, bc, wq, bq, wcq, bcq,
                                               W0, W1, gbf, smax, gz0, gz1);
  batt_kernel<<<64, 256, 0, stream>>>(c, smax, W0, W1, gbf, gz0, gz1);

  gemm_mfma_kernel<<<dim3(256, 4), 256, 0, stream>>>(gbf, l1f_Wih, l1f_bih, l1f_bhh, pref, 1024, 512);
  gemm_mfma_kernel<<<dim3(256, 4), 256, 0, stream>>>(gbf, l1b_Wih, l1b_bih, l1b_bhh, preb, 1024, 512);
  lstm_kernel<<<dim3(64, 2), 512, 0, stream>>>(pref, preb, l1f_Whh, l1b_Whh, m);

  logits_kernel<<<8192, 256, 0, stream>>>(m, W0, b0, gz0, z);
  softmax_t_kernel<<<64, 512, 0, stream>>>(z, p1);

  gemm_mfma_kernel<<<dim3(256, 4), 256, 0, stream>>>(m, l2f_Wih, l2f_bih, l2f_bhh, pref, 256, 512);
  gemm_mfma_kernel<<<dim3(256, 4), 256, 0, stream>>>(m, l2b_Wih, l2b_bih, l2b_bhh, preb, 256, 512);
  lstm_kernel<<<dim3(64, 2), 512, 0, stream>>>(pref, preb, l2f_Whh, l2b_Whh, m2);

  logits_kernel<<<8192, 256, 0, stream>>>(m2, W1, b1, gz1, z);
  softmax_t_kernel<<<64, 512, 0, stream>>>(z, p2);
}

// Round 5
// 1532.978 us; speedup vs baseline: 1.0005x; 1.0005x over previous
//
#include <hip/hip_runtime.h>
#include <hip/hip_bf16.h>
#include <cstdint>
#include <cstddef>

// Shapes: B=64, T=512, J=64, D=256, E=128, gdim=8E=1024, gates=4E=512
// ws layout (bytes), total 134,742,016 (~128.5 MiB):
//   [0,           67,108,864)  g as bf16 (32768 x 1024)   -- dead after gemm1
//        aliased: m  bf16 (32768 x 256) at offset 0
//                 m2 bf16 (32768 x 256) at offset 33,554,432
//   [67,108,864, 100,663,296)  pre_f bf16 (32768 x 512)
//   [100,663,296,134,217,728)  pre_b bf16 (32768 x 512)
//   [134,217,728,...]          gz0, gz1, smax, z  (32768 fp32 each)

typedef short short8v __attribute__((ext_vector_type(8)));
typedef float f32x4 __attribute__((ext_vector_type(4)));
typedef unsigned short ushort8v __attribute__((ext_vector_type(8)));

static __device__ __forceinline__ float bf2f(unsigned short u) {
  return __uint_as_float(((unsigned int)u) << 16);
}
static __device__ __forceinline__ unsigned short f2bf(float f) {  // RNE
  unsigned int u = __float_as_uint(f);
  return (unsigned short)((u + 0x7FFFu + ((u >> 16) & 1u)) >> 16);
}
static __device__ __forceinline__ float fsig(float x) {
  return 1.f / (1.f + __expf(-x));
}
static __device__ __forceinline__ float ftanh(float x) {
  return 1.f - 2.f / (__expf(2.f * x) + 1.f);
}

// ---------------- attention: s, softmax_j, c2q, smax, g[0:768] bf16, gz partial ----
// grid (64, 4)  block 256.  LDS ~133KB -> 1 block/CU.
__global__ __launch_bounds__(256) void attn_kernel(
    const float* __restrict__ c, const float* __restrict__ q,
    const float* __restrict__ wc, const float* __restrict__ bc,
    const float* __restrict__ wq, const float* __restrict__ bq,
    const float* __restrict__ wcq, const float* __restrict__ bcq,
    const float* __restrict__ W0, const float* __restrict__ W1,
    __hip_bfloat16* __restrict__ g, float* __restrict__ smax,
    float* __restrict__ gz0, float* __restrict__ gz1)
{
  __shared__ float qr[64][256];    // j-major (c2q: lanes sweep d, conflict-free)
  __shared__ float qrt[256][64];   // d-major (s-dot: lanes sweep j, conflict-free)
  __shared__ float qwqs[64];
  __shared__ float cwbuf[4][256];  // per-wave c*wcq row (wave-private)
  __shared__ float abuf[4][64];    // per-wave attention weights (wave-private)
  const int b = blockIdx.x;
  const int tid = threadIdx.x;
  for (int e = tid; e < 64 * 256; e += 256) {
    int j = e >> 8, d = e & 255;
    float v = q[((size_t)b * 64 + j) * 256 + d];
    qr[j][d] = v;
    qrt[d][j] = v;
  }
  __syncthreads();
  if (tid < 64) {
    float s = 0.f;
    for (int d = 0; d < 256; ++d) s += qrt[d][tid] * wq[d];
    qwqs[tid] = s + bq[0];
  }
  __syncthreads();
  const int wave = tid >> 6, lane = tid & 63;
  const float bcv = bc[0], bcqv = bcq[0];
  const int t0 = blockIdx.y * 128;
  for (int it = 0; it < 32; ++it) {
    const int trow = t0 + wave + it * 4;
    const float* crow = c + ((size_t)b * 512 + trow) * 256;
    float cv[4];
    float part = 0.f;
    #pragma unroll
    for (int r = 0; r < 4; ++r) {
      int d = lane + 64 * r;
      cv[r] = crow[d];
      cwbuf[wave][d] = cv[r] * wcq[d];
      part += cv[r] * wc[d];
    }
    #pragma unroll
    for (int off = 32; off; off >>= 1) part += __shfl_xor(part, off);
    float s = part + bcv + qwqs[lane] + bcqv;   // lane == j
    #pragma unroll 8
    for (int d = 0; d < 256; ++d) s += cwbuf[wave][d] * qrt[d][lane];
    float mx = s;
    #pragma unroll
    for (int off = 32; off; off >>= 1) mx = fmaxf(mx, __shfl_xor(mx, off));
    float e = expf(s - mx);
    float sum = e;
    #pragma unroll
    for (int off = 32; off; off >>= 1) sum += __shfl_xor(sum, off);
    abuf[wave][lane] = e / sum;
    const size_t grow = (size_t)b * 512 + trow;
    if (lane == 0) smax[grow] = mx;
    size_t row = grow * 1024;
    float az0 = 0.f, az1 = 0.f;
    #pragma unroll
    for (int r = 0; r < 4; ++r) {
      int d = lane + 64 * r;
      float acc = 0.f;
      #pragma unroll 8
      for (int j = 0; j < 64; ++j) acc += abuf[wave][j] * qr[j][d];
      float prod = cv[r] * acc;
      g[row + d]       = __float2bfloat16(cv[r]);
      g[row + 256 + d] = __float2bfloat16(acc);
      g[row + 512 + d] = __float2bfloat16(prod);
      az0 += cv[r] * W0[d] + acc * W0[256 + d] + prod * W0[512 + d];
      az1 += cv[r] * W1[d] + acc * W1[256 + d] + prod * W1[512 + d];
    }
    #pragma unroll
    for (int off = 32; off; off >>= 1) {
      az0 += __shfl_xor(az0, off);
      az1 += __shfl_xor(az1, off);
    }
    if (lane == 0) { gz0[grow] = az0; gz1[grow] = az1; }
  }
}

// ---------------- b_att softmax over t, q2c, g[768:1024] bf16, gz tail ----------
// grid 64, block 256
__global__ __launch_bounds__(256) void batt_kernel(
    const float* __restrict__ c, const float* __restrict__ smax,
    const float* __restrict__ W0, const float* __restrict__ W1,
    __hip_bfloat16* __restrict__ g,
    float* __restrict__ gz0, float* __restrict__ gz1)
{
  __shared__ float sm[512];
  __shared__ float red[4], red2[4];
  __shared__ float q2c_s[256];
  const int b = blockIdx.x, tid = threadIdx.x;
  float v0 = smax[(size_t)b * 512 + tid];
  float v1 = smax[(size_t)b * 512 + tid + 256];
  float m = fmaxf(v0, v1);
  #pragma unroll
  for (int off = 32; off; off >>= 1) m = fmaxf(m, __shfl_xor(m, off));
  if ((tid & 63) == 0) red[tid >> 6] = m;
  __syncthreads();
  float M = fmaxf(fmaxf(red[0], red[1]), fmaxf(red[2], red[3]));
  float e0 = expf(v0 - M), e1 = expf(v1 - M);
  float ssum = e0 + e1;
  #pragma unroll
  for (int off = 32; off; off >>= 1) ssum += __shfl_xor(ssum, off);
  if ((tid & 63) == 0) red2[tid >> 6] = ssum;
  __syncthreads();
  float S = red2[0] + red2[1] + red2[2] + red2[3];
  sm[tid] = e0 / S;
  sm[tid + 256] = e1 / S;
  __syncthreads();
  float acc = 0.f;
  #pragma unroll 8
  for (int t = 0; t < 512; ++t) acc += sm[t] * c[((size_t)b * 512 + t) * 256 + tid];
  q2c_s[tid] = acc;
  __syncthreads();
  const int wave = tid >> 6, lane = tid & 63;
  float qv[4], w0c[4], w1c[4];
  #pragma unroll
  for (int r = 0; r < 4; ++r) {
    int d = lane + 64 * r;
    qv[r]  = q2c_s[d];
    w0c[r] = W0[768 + d];
    w1c[r] = W1[768 + d];
  }
  for (int t = wave; t < 512; t += 4) {
    size_t row = (size_t)b * 512 + t;
    float s0 = 0.f, s1 = 0.f;
    #pragma unroll
    for (int r = 0; r < 4; ++r) {
      int d = lane + 64 * r;
      float v = c[row * 256 + d];
      float gv = v * qv[r];
      g[row * 1024 + 768 + d] = __float2bfloat16(gv);
      s0 += gv * w0c[r];
      s1 += gv * w1c[r];
    }
    #pragma unroll
    for (int off = 32; off; off >>= 1) {
      s0 += __shfl_xor(s0, off);
      s1 += __shfl_xor(s1, off);
    }
    if (lane == 0) { gz0[row] += s0; gz1[row] += s1; }
  }
}

// ---------------- MFMA GEMM: Ybf16[M,N] = Xbf16[M,K] @ Wfp32[N,K]^T + b1 + b2 ---
// grid (M/128, N/128), block 256 (4 waves, each 64x64). BK=64. W cvt'd inline.
__global__ __launch_bounds__(256) void gemm_mfma_kernel(
    const __hip_bfloat16* __restrict__ Xg, const float* __restrict__ W,
    const float* __restrict__ bias1, const float* __restrict__ bias2,
    __hip_bfloat16* __restrict__ Y, int K, int N)
{
  __shared__ unsigned short Xs[128 * 72];  // row stride 72 (+8 pad = 16B, b128-aligned)
  __shared__ unsigned short Ws[128 * 72];
  const unsigned short* X = (const unsigned short*)Xg;
  const int tid = threadIdx.x;
  const int m0 = blockIdx.x * 128, n0 = blockIdx.y * 128;
  const int lane = tid & 63, wave = tid >> 6;
  const int wr = wave >> 1, wc = wave & 1;
  const int frow = lane & 15, fk = (lane >> 4) * 8;

  f32x4 acc[4][4] = {};
  for (int kt = 0; kt < K; kt += 64) {
    #pragma unroll
    for (int i = 0; i < 4; ++i) {
      int cidx = tid + 256 * i;          // 0..1023
      int row = cidx >> 3, kc = cidx & 7;
      ushort8v v = *(const ushort8v*)&X[(size_t)(m0 + row) * K + kt + kc * 8];
      *(ushort8v*)&Xs[row * 72 + kc * 8] = v;
    }
    #pragma unroll
    for (int i = 0; i < 4; ++i) {
      int cidx = tid + 256 * i;
      int row = cidx >> 3, kc = cidx & 7;
      const float* wp = &W[(size_t)(n0 + row) * K + kt + kc * 8];
      float4 f0 = *(const float4*)wp;
      float4 f1 = *(const float4*)(wp + 4);
      ushort8v v;
      v[0] = f2bf(f0.x); v[1] = f2bf(f0.y); v[2] = f2bf(f0.z); v[3] = f2bf(f0.w);
      v[4] = f2bf(f1.x); v[5] = f2bf(f1.y); v[6] = f2bf(f1.z); v[7] = f2bf(f1.w);
      *(ushort8v*)&Ws[row * 72 + kc * 8] = v;
    }
    __syncthreads();
    #pragma unroll
    for (int kk = 0; kk < 64; kk += 32) {
      short8v a[4], bfr[4];
      #pragma unroll
      for (int i = 0; i < 4; ++i)
        a[i] = *(const short8v*)&Xs[(wr * 64 + i * 16 + frow) * 72 + kk + fk];
      #pragma unroll
      for (int j = 0; j < 4; ++j)
        bfr[j] = *(const short8v*)&Ws[(wc * 64 + j * 16 + frow) * 72 + kk + fk];
      #pragma unroll
      for (int i = 0; i < 4; ++i)
        #pragma unroll
        for (int j = 0; j < 4; ++j)
          acc[i][j] = __builtin_amdgcn_mfma_f32_16x16x32_bf16(a[i], bfr[j], acc[i][j], 0, 0, 0);
    }
    __syncthreads();
  }
  const int r0 = (lane >> 4) * 4;
  #pragma unroll
  for (int j = 0; j < 4; ++j) {
    int col = n0 + wc * 64 + j * 16 + (lane & 15);
    float bsum = bias1[col] + bias2[col];
    #pragma unroll
    for (int i = 0; i < 4; ++i) {
      int rowb = m0 + wr * 64 + i * 16 + r0;
      #pragma unroll
      for (int r = 0; r < 4; ++r)
        Y[(size_t)(rowb + r) * N + col] = __float2bfloat16(acc[i][j][r] + bsum);
    }
  }
}

// ---------------- LSTM recurrence (wave-local gates, 1 barrier/step) ----------
// grid (64, 2) block 512, __launch_bounds__(512,2).
// Whh row held in f32x4 w4[32] -- ext_vector, NO address-taking, static unrolled
// indices -> mem2reg promotes to 128 VGPRs (check VGPR_Count >= 150).
// wave w, lane l: cell j = w*16+(l&15), gate q = l>>4, row = q*128+j.
// h double-buffered in LDS; gates gathered via 4 in-wave shuffles.
__global__ __launch_bounds__(512, 2) void lstm_kernel(
    const __hip_bfloat16* __restrict__ pre_f, const __hip_bfloat16* __restrict__ pre_b,
    const float* __restrict__ Whh_f, const float* __restrict__ Whh_b,
    __hip_bfloat16* __restrict__ out)
{
  const int b = blockIdx.x, dir = blockIdx.y;
  const unsigned short* __restrict__ pre =
      (const unsigned short*)(dir ? pre_b : pre_f);
  const float* __restrict__ Whh = dir ? Whh_b : Whh_f;
  const int off = dir ? 128 : 0;
  const int tid = threadIdx.x;
  const int wave = tid >> 6, lane = tid & 63;
  const int q = lane >> 4;                  // 0=i 1=f 2=g 3=o
  const int j = wave * 16 + (lane & 15);    // cell 0..127
  const int row = q * 128 + j;              // gate row 0..511
  f32x4 w4[32];
  const f32x4* wrow = (const f32x4*)(Whh + (size_t)row * 128);
  #pragma unroll
  for (int k4 = 0; k4 < 32; ++k4) w4[k4] = wrow[k4];
  __shared__ float hbuf[2][128];
  if (tid < 128) { hbuf[0][tid] = 0.f; hbuf[1][tid] = 0.f; }
  float cst = 0.f;
  __syncthreads();
  const size_t base = (size_t)b * 512;
  int t = dir ? 511 : 0;
  const int tstep = dir ? -1 : 1;
  float pcur = bf2f(pre[(base + t) * 512 + row]);
  int cur = 0;
  const int l0 = lane & 15;
  for (int s = 0; s < 512; ++s) {
    float pnext = 0.f;
    if (s < 511) pnext = bf2f(pre[(base + t + tstep) * 512 + row]);
    const f32x4* h4 = (const f32x4*)hbuf[cur];
    float a0 = pcur, a1 = 0.f, a2 = 0.f, a3 = 0.f;
    #pragma unroll
    for (int k4 = 0; k4 < 32; ++k4) {
      f32x4 hv = h4[k4];
      a0 += w4[k4].x * hv.x; a1 += w4[k4].y * hv.y;
      a2 += w4[k4].z * hv.z; a3 += w4[k4].w * hv.w;
    }
    float preact = (a0 + a1) + (a2 + a3);
    float a = (q == 2) ? ftanh(preact) : fsig(preact);
    float gi_ = __shfl(a, l0);
    float gf_ = __shfl(a, l0 + 16);
    float gg_ = __shfl(a, l0 + 32);
    float go_ = __shfl(a, l0 + 48);
    cst = gf_ * cst + gi_ * gg_;             // replicated across the 4 lane groups
    float hv = go_ * ftanh(cst);
    if (q == 0) {
      hbuf[cur ^ 1][j] = hv;
      out[(base + t) * 256 + off + j] = __float2bfloat16(hv);
    }
    __syncthreads();
    pcur = pnext;
    t += tstep;
    cur ^= 1;
  }
}

// ---------------- logits: z[row] = gz[row] + m_row(bf16) . W[1024:1280] + bias ----
// grid 8192, block 256 (wave per row)
__global__ __launch_bounds__(256) void logits_kernel(
    const __hip_bfloat16* __restrict__ m, const float* __restrict__ W,
    const float* __restrict__ bias, const float* __restrict__ gz,
    float* __restrict__ z)
{
  const int row = blockIdx.x * 4 + (threadIdx.x >> 6);
  const int lane = threadIdx.x & 63;
  const unsigned short* mrow = (const unsigned short*)m + (size_t)row * 256;
  float acc = 0.f;
  #pragma unroll
  for (int i = 0; i < 4; ++i) acc += bf2f(mrow[lane + 64 * i]) * W[1024 + lane + 64 * i];
  #pragma unroll
  for (int off = 32; off; off >>= 1) acc += __shfl_xor(acc, off);
  if (lane == 0) z[row] = acc + gz[row] + bias[0];
}

// ---------------- softmax over t ----------------
// grid 64, block 512
__global__ __launch_bounds__(512) void softmax_t_kernel(
    const float* __restrict__ z, float* __restrict__ p)
{
  const int b = blockIdx.x, t = threadIdx.x;
  __shared__ float red[8], red2[8];
  float v = z[(size_t)b * 512 + t];
  float m = v;
  #pragma unroll
  for (int off = 32; off; off >>= 1) m = fmaxf(m, __shfl_xor(m, off));
  if ((t & 63) == 0) red[t >> 6] = m;
  __syncthreads();
  float M = red[0];
  #pragma unroll
  for (int i = 1; i < 8; ++i) M = fmaxf(M, red[i]);
  float e = expf(v - M);
  float s = e;
  #pragma unroll
  for (int off = 32; off; off >>= 1) s += __shfl_xor(s, off);
  if ((t & 63) == 0) red2[t >> 6] = s;
  __syncthreads();
  float S = red2[0];
  #pragma unroll
  for (int i = 1; i < 8; ++i) S += red2[i];
  p[(size_t)b * 512 + t] = e / S;
}

extern "C" void kernel_launch(void* const* d_in, const int* in_sizes, int n_in,
                              void* d_out, int out_size, void* d_ws, size_t ws_size,
                              hipStream_t stream)
{
  const float* c   = (const float*)d_in[0];
  const float* q   = (const float*)d_in[1];
  const float* wc  = (const float*)d_in[2];
  const float* bc  = (const float*)d_in[3];
  const float* wq  = (const float*)d_in[4];
  const float* bq  = (const float*)d_in[5];
  const float* wcq = (const float*)d_in[6];
  const float* bcq = (const float*)d_in[7];
  const float* l1f_Wih = (const float*)d_in[8];
  const float* l1f_Whh = (const float*)d_in[9];
  const float* l1f_bih = (const float*)d_in[10];
  const float* l1f_bhh = (const float*)d_in[11];
  const float* l1b_Wih = (const float*)d_in[12];
  const float* l1b_Whh = (const float*)d_in[13];
  const float* l1b_bih = (const float*)d_in[14];
  const float* l1b_bhh = (const float*)d_in[15];
  const float* l2f_Wih = (const float*)d_in[16];
  const float* l2f_Whh = (const float*)d_in[17];
  const float* l2f_bih = (const float*)d_in[18];
  const float* l2f_bhh = (const float*)d_in[19];
  const float* l2b_Wih = (const float*)d_in[20];
  const float* l2b_Whh = (const float*)d_in[21];
  const float* l2b_bih = (const float*)d_in[22];
  const float* l2b_bhh = (const float*)d_in[23];
  const float* W0 = (const float*)d_in[24];
  const float* b0 = (const float*)d_in[25];
  const float* W1 = (const float*)d_in[26];
  const float* b1 = (const float*)d_in[27];

  const size_t required = 134742016u;
  if (ws_size < required) return;

  char* wsb = (char*)d_ws;
  __hip_bfloat16* gbf = (__hip_bfloat16*)wsb;                  // 67,108,864 B
  __hip_bfloat16* m   = (__hip_bfloat16*)wsb;                  // alias (g dead after gemm1)
  __hip_bfloat16* m2  = (__hip_bfloat16*)(wsb + 33554432);     // alias
  __hip_bfloat16* pref = (__hip_bfloat16*)(wsb + 67108864);    // 33,554,432 B
  __hip_bfloat16* preb = (__hip_bfloat16*)(wsb + 100663296);   // 33,554,432 B
  float* gz0  = (float*)(wsb + 134217728);
  float* gz1  = gz0 + 32768;
  float* smax = gz1 + 32768;
  float* z    = smax + 32768;
  float* p1   = (float*)d_out;
  float* p2   = p1 + 32768;

  attn_kernel<<<dim3(64, 4), 256, 0, stream>>>(c, q, wc, bc, wq, bq, wcq, bcq,
                                               W0, W1, gbf, smax, gz0, gz1);
  batt_kernel<<<64, 256, 0, stream>>>(c, smax, W0, W1, gbf, gz0, gz1);

  gemm_mfma_kernel<<<dim3(256, 4), 256, 0, stream>>>(gbf, l1f_Wih, l1f_bih, l1f_bhh, pref, 1024, 512);
  gemm_mfma_kernel<<<dim3(256, 4), 256, 0, stream>>>(gbf, l1b_Wih, l1b_bih, l1b_bhh, preb, 1024, 512);
  lstm_kernel<<<dim3(64, 2), 512, 0, stream>>>(pref, preb, l1f_Whh, l1b_Whh, m);

  logits_kernel<<<8192, 256, 0, stream>>>(m, W0, b0, gz0, z);
  softmax_t_kernel<<<64, 512, 0, stream>>>(z, p1);

  gemm_mfma_kernel<<<dim3(256, 4), 256, 0, stream>>>(m, l2f_Wih, l2f_bih, l2f_bhh, pref, 256, 512);
  gemm_mfma_kernel<<<dim3(256, 4), 256, 0, stream>>>(m, l2b_Wih, l2b_bih, l2b_bhh, preb, 256, 512);
  lstm_kernel<<<dim3(64, 2), 512, 0, stream>>>(pref, preb, l2f_Whh, l2b_Whh, m2);

  logits_kernel<<<8192, 256, 0, stream>>>(m2, W1, b1, gz1, z);
  softmax_t_kernel<<<64, 512, 0, stream>>>(z, p2);
}

// Round 6
// 1254.867 us; speedup vs baseline: 1.2222x; 1.2216x over previous
//
#include <hip/hip_runtime.h>
#include <hip/hip_bf16.h>
#include <cstdint>
#include <cstddef>

// Shapes: B=64, T=512, J=64, D=256, E=128, gdim=8E=1024, gates=4E=512
// ws layout (bytes), total 134,742,016 (~128.5 MiB):
//   [0,           67,108,864)  g as bf16 (32768 x 1024)   -- dead after gemm1
//        aliased: m  bf16 (32768 x 256) at offset 0
//                 m2 bf16 (32768 x 256) at offset 33,554,432
//   [67,108,864, 100,663,296)  pre_f bf16 (32768 x 512)  [cell][gate] layout!
//   [100,663,296,134,217,728)  pre_b bf16 (32768 x 512)  [cell][gate] layout!
//   [134,217,728,...]          gz0, gz1, smax, z  (32768 fp32 each)
// pre layout: pre[row][j*4+q] = gate q (0=i,1=f,2=g,3=o) of cell j.

typedef short short8v __attribute__((ext_vector_type(8)));
typedef float f32x4 __attribute__((ext_vector_type(4)));
typedef unsigned short ushort8v __attribute__((ext_vector_type(8)));
typedef unsigned short ushort4v __attribute__((ext_vector_type(4)));

static __device__ __forceinline__ float bf2f(unsigned short u) {
  return __uint_as_float(((unsigned int)u) << 16);
}
static __device__ __forceinline__ unsigned short f2bf(float f) {  // RNE
  unsigned int u = __float_as_uint(f);
  return (unsigned short)((u + 0x7FFFu + ((u >> 16) & 1u)) >> 16);
}
static __device__ __forceinline__ float fsig(float x) {
  return 1.f / (1.f + __expf(-x));
}
static __device__ __forceinline__ float ftanh(float x) {
  return 1.f - 2.f / (__expf(2.f * x) + 1.f);
}

// ---------------- attention: s, softmax_j, c2q, smax, g[0:768] bf16, gz partial ----
// grid (64, 4)  block 256.  LDS ~133KB -> 1 block/CU.
__global__ __launch_bounds__(256) void attn_kernel(
    const float* __restrict__ c, const float* __restrict__ q,
    const float* __restrict__ wc, const float* __restrict__ bc,
    const float* __restrict__ wq, const float* __restrict__ bq,
    const float* __restrict__ wcq, const float* __restrict__ bcq,
    const float* __restrict__ W0, const float* __restrict__ W1,
    __hip_bfloat16* __restrict__ g, float* __restrict__ smax,
    float* __restrict__ gz0, float* __restrict__ gz1)
{
  __shared__ float qr[64][256];    // j-major (c2q: lanes sweep d, conflict-free)
  __shared__ float qrt[256][64];   // d-major (s-dot: lanes sweep j, conflict-free)
  __shared__ float qwqs[64];
  __shared__ float cwbuf[4][256];  // per-wave c*wcq row (wave-private)
  __shared__ float abuf[4][64];    // per-wave attention weights (wave-private)
  const int b = blockIdx.x;
  const int tid = threadIdx.x;
  for (int e = tid; e < 64 * 256; e += 256) {
    int j = e >> 8, d = e & 255;
    float v = q[((size_t)b * 64 + j) * 256 + d];
    qr[j][d] = v;
    qrt[d][j] = v;
  }
  __syncthreads();
  if (tid < 64) {
    float s = 0.f;
    for (int d = 0; d < 256; ++d) s += qrt[d][tid] * wq[d];
    qwqs[tid] = s + bq[0];
  }
  __syncthreads();
  const int wave = tid >> 6, lane = tid & 63;
  const float bcv = bc[0], bcqv = bcq[0];
  const int t0 = blockIdx.y * 128;
  for (int it = 0; it < 32; ++it) {
    const int trow = t0 + wave + it * 4;
    const float* crow = c + ((size_t)b * 512 + trow) * 256;
    float cv[4];
    float part = 0.f;
    #pragma unroll
    for (int r = 0; r < 4; ++r) {
      int d = lane + 64 * r;
      cv[r] = crow[d];
      cwbuf[wave][d] = cv[r] * wcq[d];
      part += cv[r] * wc[d];
    }
    #pragma unroll
    for (int off = 32; off; off >>= 1) part += __shfl_xor(part, off);
    float s = part + bcv + qwqs[lane] + bcqv;   // lane == j
    #pragma unroll 8
    for (int d = 0; d < 256; ++d) s += cwbuf[wave][d] * qrt[d][lane];
    float mx = s;
    #pragma unroll
    for (int off = 32; off; off >>= 1) mx = fmaxf(mx, __shfl_xor(mx, off));
    float e = expf(s - mx);
    float sum = e;
    #pragma unroll
    for (int off = 32; off; off >>= 1) sum += __shfl_xor(sum, off);
    abuf[wave][lane] = e / sum;
    const size_t grow = (size_t)b * 512 + trow;
    if (lane == 0) smax[grow] = mx;
    size_t row = grow * 1024;
    float az0 = 0.f, az1 = 0.f;
    #pragma unroll
    for (int r = 0; r < 4; ++r) {
      int d = lane + 64 * r;
      float acc = 0.f;
      #pragma unroll 8
      for (int j = 0; j < 64; ++j) acc += abuf[wave][j] * qr[j][d];
      float prod = cv[r] * acc;
      g[row + d]       = __float2bfloat16(cv[r]);
      g[row + 256 + d] = __float2bfloat16(acc);
      g[row + 512 + d] = __float2bfloat16(prod);
      az0 += cv[r] * W0[d] + acc * W0[256 + d] + prod * W0[512 + d];
      az1 += cv[r] * W1[d] + acc * W1[256 + d] + prod * W1[512 + d];
    }
    #pragma unroll
    for (int off = 32; off; off >>= 1) {
      az0 += __shfl_xor(az0, off);
      az1 += __shfl_xor(az1, off);
    }
    if (lane == 0) { gz0[grow] = az0; gz1[grow] = az1; }
  }
}

// ---------------- b_att softmax over t, q2c, g[768:1024] bf16, gz tail ----------
// grid 64, block 256
__global__ __launch_bounds__(256) void batt_kernel(
    const float* __restrict__ c, const float* __restrict__ smax,
    const float* __restrict__ W0, const float* __restrict__ W1,
    __hip_bfloat16* __restrict__ g,
    float* __restrict__ gz0, float* __restrict__ gz1)
{
  __shared__ float sm[512];
  __shared__ float red[4], red2[4];
  __shared__ float q2c_s[256];
  const int b = blockIdx.x, tid = threadIdx.x;
  float v0 = smax[(size_t)b * 512 + tid];
  float v1 = smax[(size_t)b * 512 + tid + 256];
  float m = fmaxf(v0, v1);
  #pragma unroll
  for (int off = 32; off; off >>= 1) m = fmaxf(m, __shfl_xor(m, off));
  if ((tid & 63) == 0) red[tid >> 6] = m;
  __syncthreads();
  float M = fmaxf(fmaxf(red[0], red[1]), fmaxf(red[2], red[3]));
  float e0 = expf(v0 - M), e1 = expf(v1 - M);
  float ssum = e0 + e1;
  #pragma unroll
  for (int off = 32; off; off >>= 1) ssum += __shfl_xor(ssum, off);
  if ((tid & 63) == 0) red2[tid >> 6] = ssum;
  __syncthreads();
  float S = red2[0] + red2[1] + red2[2] + red2[3];
  sm[tid] = e0 / S;
  sm[tid + 256] = e1 / S;
  __syncthreads();
  float acc = 0.f;
  #pragma unroll 8
  for (int t = 0; t < 512; ++t) acc += sm[t] * c[((size_t)b * 512 + t) * 256 + tid];
  q2c_s[tid] = acc;
  __syncthreads();
  const int wave = tid >> 6, lane = tid & 63;
  float qv[4], w0c[4], w1c[4];
  #pragma unroll
  for (int r = 0; r < 4; ++r) {
    int d = lane + 64 * r;
    qv[r]  = q2c_s[d];
    w0c[r] = W0[768 + d];
    w1c[r] = W1[768 + d];
  }
  for (int t = wave; t < 512; t += 4) {
    size_t row = (size_t)b * 512 + t;
    float s0 = 0.f, s1 = 0.f;
    #pragma unroll
    for (int r = 0; r < 4; ++r) {
      int d = lane + 64 * r;
      float v = c[row * 256 + d];
      float gv = v * qv[r];
      g[row * 1024 + 768 + d] = __float2bfloat16(gv);
      s0 += gv * w0c[r];
      s1 += gv * w1c[r];
    }
    #pragma unroll
    for (int off = 32; off; off >>= 1) {
      s0 += __shfl_xor(s0, off);
      s1 += __shfl_xor(s1, off);
    }
    if (lane == 0) { gz0[row] += s0; gz1[row] += s1; }
  }
}

// ---------------- MFMA GEMM: pre[M,512] = Xbf16[M,K] @ Wfp32[512,K]^T + b1 + b2 ---
// grid (M/128, 4), block 256 (4 waves, each 64x64). BK=64. W cvt'd inline.
// Output stored PERMUTED: pre[row][ (col&127)*4 + (col>>7) ]  ([cell][gate]).
__global__ __launch_bounds__(256) void gemm_mfma_kernel(
    const __hip_bfloat16* __restrict__ Xg, const float* __restrict__ W,
    const float* __restrict__ bias1, const float* __restrict__ bias2,
    __hip_bfloat16* __restrict__ Y, int K, int N)
{
  __shared__ unsigned short Xs[128 * 72];  // row stride 72 (+8 pad = 16B, b128-aligned)
  __shared__ unsigned short Ws[128 * 72];
  const unsigned short* X = (const unsigned short*)Xg;
  const int tid = threadIdx.x;
  const int m0 = blockIdx.x * 128, n0 = blockIdx.y * 128;
  const int lane = tid & 63, wave = tid >> 6;
  const int wr = wave >> 1, wc = wave & 1;
  const int frow = lane & 15, fk = (lane >> 4) * 8;

  f32x4 acc[4][4] = {};
  for (int kt = 0; kt < K; kt += 64) {
    #pragma unroll
    for (int i = 0; i < 4; ++i) {
      int cidx = tid + 256 * i;          // 0..1023
      int row = cidx >> 3, kc = cidx & 7;
      ushort8v v = *(const ushort8v*)&X[(size_t)(m0 + row) * K + kt + kc * 8];
      *(ushort8v*)&Xs[row * 72 + kc * 8] = v;
    }
    #pragma unroll
    for (int i = 0; i < 4; ++i) {
      int cidx = tid + 256 * i;
      int row = cidx >> 3, kc = cidx & 7;
      const float* wp = &W[(size_t)(n0 + row) * K + kt + kc * 8];
      float4 f0 = *(const float4*)wp;
      float4 f1 = *(const float4*)(wp + 4);
      ushort8v v;
      v[0] = f2bf(f0.x); v[1] = f2bf(f0.y); v[2] = f2bf(f0.z); v[3] = f2bf(f0.w);
      v[4] = f2bf(f1.x); v[5] = f2bf(f1.y); v[6] = f2bf(f1.z); v[7] = f2bf(f1.w);
      *(ushort8v*)&Ws[row * 72 + kc * 8] = v;
    }
    __syncthreads();
    #pragma unroll
    for (int kk = 0; kk < 64; kk += 32) {
      short8v a[4], bfr[4];
      #pragma unroll
      for (int i = 0; i < 4; ++i)
        a[i] = *(const short8v*)&Xs[(wr * 64 + i * 16 + frow) * 72 + kk + fk];
      #pragma unroll
      for (int j = 0; j < 4; ++j)
        bfr[j] = *(const short8v*)&Ws[(wc * 64 + j * 16 + frow) * 72 + kk + fk];
      #pragma unroll
      for (int i = 0; i < 4; ++i)
        #pragma unroll
        for (int j = 0; j < 4; ++j)
          acc[i][j] = __builtin_amdgcn_mfma_f32_16x16x32_bf16(a[i], bfr[j], acc[i][j], 0, 0, 0);
    }
    __syncthreads();
  }
  const int r0 = (lane >> 4) * 4;
  #pragma unroll
  for (int j = 0; j < 4; ++j) {
    int col = n0 + wc * 64 + j * 16 + (lane & 15);
    int colp = (col & 127) * 4 + (col >> 7);   // [cell][gate] permuted layout
    float bsum = bias1[col] + bias2[col];
    #pragma unroll
    for (int i = 0; i < 4; ++i) {
      int rowb = m0 + wr * 64 + i * 16 + r0;
      #pragma unroll
      for (int r = 0; r < 4; ++r)
        Y[(size_t)(rowb + r) * N + colp] = __float2bfloat16(acc[i][j][r] + bsum);
    }
  }
}

// ---------------- LSTM recurrence via MFMA ----------------
// grid (64, 2) block 512 (8 waves). Per step: gates[512] = Whh·h via
// mfma_f32_16x16x32_bf16 with A = h broadcast into all 16 rows (each 16-lane
// group reads the SAME LDS address -> every D row equals h·B; layout-proof).
// B = Whh bf16 fragments resident in VGPRs (16 x short8v = 64 VGPRs, asm-pinned;
// the fp32->bf16 convert chain is not remat-able, unlike r4/r5's raw loads).
// Wave w owns cells w*16..w*16+15; its 4 N-tiles are gates i,f,g,o of those
// cells, so lane l holds all 4 gates of cell w*16+(l&15) -> no shuffles.
// 4 ds_read_b128 + 16 MFMA + 5 exp per wave per step; 1 barrier/step.
__global__ __launch_bounds__(512, 2) void lstm_kernel(
    const __hip_bfloat16* __restrict__ pre_f, const __hip_bfloat16* __restrict__ pre_b,
    const float* __restrict__ Whh_f, const float* __restrict__ Whh_b,
    __hip_bfloat16* __restrict__ out)
{
  const int b = blockIdx.x, dir = blockIdx.y;
  const unsigned short* __restrict__ pre =
      (const unsigned short*)(dir ? pre_b : pre_f);
  const float* __restrict__ Whh = dir ? Whh_b : Whh_f;
  const int off = dir ? 128 : 0;
  const int tid = threadIdx.x;
  const int wave = tid >> 6, lane = tid & 63;
  const int cl = lane & 15;            // col / cell-within-wave
  const int kg = lane >> 4;            // k-group 0..3
  const int cell = wave * 16 + cl;     // 0..127

  // B fragments: bf[q][kt] = Whh[q*128+cell][kt*32 + kg*8 .. +8] as bf16
  short8v bf[4][4];
  #pragma unroll
  for (int q = 0; q < 4; ++q) {
    const float* wrow = Whh + (size_t)(q * 128 + cell) * 128;
    #pragma unroll
    for (int kt = 0; kt < 4; ++kt) {
      const float* wp = wrow + kt * 32 + kg * 8;
      float4 f0 = *(const float4*)wp;
      float4 f1 = *(const float4*)(wp + 4);
      short8v v;
      v[0] = (short)f2bf(f0.x); v[1] = (short)f2bf(f0.y);
      v[2] = (short)f2bf(f0.z); v[3] = (short)f2bf(f0.w);
      v[4] = (short)f2bf(f1.x); v[5] = (short)f2bf(f1.y);
      v[6] = (short)f2bf(f1.z); v[7] = (short)f2bf(f1.w);
      bf[q][kt] = v;
      asm volatile("" : "+v"(bf[q][kt]));   // pin: forbid remat/spill-to-reload
    }
  }

  __shared__ unsigned short hbuf[2][128];   // h as bf16, double-buffered
  if (tid < 128) { hbuf[0][tid] = 0; hbuf[1][tid] = 0; }
  __syncthreads();

  const size_t base = (size_t)b * 512;
  int t = dir ? 511 : 0;
  const int tstep = dir ? -1 : 1;
  ushort4v p4 = *(const ushort4v*)(pre + (base + t) * 512 + cell * 4);
  int cur = 0;
  float cst = 0.f;
  for (int s = 0; s < 512; ++s) {
    ushort4v pn = p4;
    if (s < 511) pn = *(const ushort4v*)(pre + (base + t + tstep) * 512 + cell * 4);
    // A fragments: each 16-lane group reads the same 16B of h -> broadcast
    const unsigned short* hb = hbuf[cur];
    short8v a0 = *(const short8v*)(hb +  0 + kg * 8);
    short8v a1 = *(const short8v*)(hb + 32 + kg * 8);
    short8v a2 = *(const short8v*)(hb + 64 + kg * 8);
    short8v a3 = *(const short8v*)(hb + 96 + kg * 8);
    f32x4 acc[4];
    #pragma unroll
    for (int q = 0; q < 4; ++q) {
      float pv = bf2f(p4[q]);
      acc[q] = (f32x4){pv, pv, pv, pv};
      acc[q] = __builtin_amdgcn_mfma_f32_16x16x32_bf16(a0, bf[q][0], acc[q], 0, 0, 0);
      acc[q] = __builtin_amdgcn_mfma_f32_16x16x32_bf16(a1, bf[q][1], acc[q], 0, 0, 0);
      acc[q] = __builtin_amdgcn_mfma_f32_16x16x32_bf16(a2, bf[q][2], acc[q], 0, 0, 0);
      acc[q] = __builtin_amdgcn_mfma_f32_16x16x32_bf16(a3, bf[q][3], acc[q], 0, 0, 0);
    }
    float gi_ = fsig(acc[0][0]);
    float gf_ = fsig(acc[1][0]);
    float gg_ = ftanh(acc[2][0]);
    float go_ = fsig(acc[3][0]);
    cst = gf_ * cst + gi_ * gg_;          // replicated across the 4 k-groups
    float hv = go_ * ftanh(cst);
    if (lane < 16) {
      hbuf[cur ^ 1][cell] = f2bf(hv);
      out[(base + t) * 256 + off + cell] = __float2bfloat16(hv);
    }
    __syncthreads();
    p4 = pn;
    t += tstep;
    cur ^= 1;
  }
}

// ---------------- logits: z[row] = gz[row] + m_row(bf16) . W[1024:1280] + bias ----
// grid 8192, block 256 (wave per row)
__global__ __launch_bounds__(256) void logits_kernel(
    const __hip_bfloat16* __restrict__ m, const float* __restrict__ W,
    const float* __restrict__ bias, const float* __restrict__ gz,
    float* __restrict__ z)
{
  const int row = blockIdx.x * 4 + (threadIdx.x >> 6);
  const int lane = threadIdx.x & 63;
  const unsigned short* mrow = (const unsigned short*)m + (size_t)row * 256;
  float acc = 0.f;
  #pragma unroll
  for (int i = 0; i < 4; ++i) acc += bf2f(mrow[lane + 64 * i]) * W[1024 + lane + 64 * i];
  #pragma unroll
  for (int off = 32; off; off >>= 1) acc += __shfl_xor(acc, off);
  if (lane == 0) z[row] = acc + gz[row] + bias[0];
}

// ---------------- softmax over t ----------------
// grid 64, block 512
__global__ __launch_bounds__(512) void softmax_t_kernel(
    const float* __restrict__ z, float* __restrict__ p)
{
  const int b = blockIdx.x, t = threadIdx.x;
  __shared__ float red[8], red2[8];
  float v = z[(size_t)b * 512 + t];
  float m = v;
  #pragma unroll
  for (int off = 32; off; off >>= 1) m = fmaxf(m, __shfl_xor(m, off));
  if ((t & 63) == 0) red[t >> 6] = m;
  __syncthreads();
  float M = red[0];
  #pragma unroll
  for (int i = 1; i < 8; ++i) M = fmaxf(M, red[i]);
  float e = expf(v - M);
  float s = e;
  #pragma unroll
  for (int off = 32; off; off >>= 1) s += __shfl_xor(s, off);
  if ((t & 63) == 0) red2[t >> 6] = s;
  __syncthreads();
  float S = red2[0];
  #pragma unroll
  for (int i = 1; i < 8; ++i) S += red2[i];
  p[(size_t)b * 512 + t] = e / S;
}

extern "C" void kernel_launch(void* const* d_in, const int* in_sizes, int n_in,
                              void* d_out, int out_size, void* d_ws, size_t ws_size,
                              hipStream_t stream)
{
  const float* c   = (const float*)d_in[0];
  const float* q   = (const float*)d_in[1];
  const float* wc  = (const float*)d_in[2];
  const float* bc  = (const float*)d_in[3];
  const float* wq  = (const float*)d_in[4];
  const float* bq  = (const float*)d_in[5];
  const float* wcq = (const float*)d_in[6];
  const float* bcq = (const float*)d_in[7];
  const float* l1f_Wih = (const float*)d_in[8];
  const float* l1f_Whh = (const float*)d_in[9];
  const float* l1f_bih = (const float*)d_in[10];
  const float* l1f_bhh = (const float*)d_in[11];
  const float* l1b_Wih = (const float*)d_in[12];
  const float* l1b_Whh = (const float*)d_in[13];
  const float* l1b_bih = (const float*)d_in[14];
  const float* l1b_bhh = (const float*)d_in[15];
  const float* l2f_Wih = (const float*)d_in[16];
  const float* l2f_Whh = (const float*)d_in[17];
  const float* l2f_bih = (const float*)d_in[18];
  const float* l2f_bhh = (const float*)d_in[19];
  const float* l2b_Wih = (const float*)d_in[20];
  const float* l2b_Whh = (const float*)d_in[21];
  const float* l2b_bih = (const float*)d_in[22];
  const float* l2b_bhh = (const float*)d_in[23];
  const float* W0 = (const float*)d_in[24];
  const float* b0 = (const float*)d_in[25];
  const float* W1 = (const float*)d_in[26];
  const float* b1 = (const float*)d_in[27];

  const size_t required = 134742016u;
  if (ws_size < required) return;

  char* wsb = (char*)d_ws;
  __hip_bfloat16* gbf = (__hip_bfloat16*)wsb;                  // 67,108,864 B
  __hip_bfloat16* m   = (__hip_bfloat16*)wsb;                  // alias (g dead after gemm1)
  __hip_bfloat16* m2  = (__hip_bfloat16*)(wsb + 33554432);     // alias
  __hip_bfloat16* pref = (__hip_bfloat16*)(wsb + 67108864);    // 33,554,432 B
  __hip_bfloat16* preb = (__hip_bfloat16*)(wsb + 100663296);   // 33,554,432 B
  float* gz0  = (float*)(wsb + 134217728);
  float* gz1  = gz0 + 32768;
  float* smax = gz1 + 32768;
  float* z    = smax + 32768;
  float* p1   = (float*)d_out;
  float* p2   = p1 + 32768;

  attn_kernel<<<dim3(64, 4), 256, 0, stream>>>(c, q, wc, bc, wq, bq, wcq, bcq,
                                               W0, W1, gbf, smax, gz0, gz1);
  batt_kernel<<<64, 256, 0, stream>>>(c, smax, W0, W1, gbf, gz0, gz1);

  gemm_mfma_kernel<<<dim3(256, 4), 256, 0, stream>>>(gbf, l1f_Wih, l1f_bih, l1f_bhh, pref, 1024, 512);
  gemm_mfma_kernel<<<dim3(256, 4), 256, 0, stream>>>(gbf, l1b_Wih, l1b_bih, l1b_bhh, preb, 1024, 512);
  lstm_kernel<<<dim3(64, 2), 512, 0, stream>>>(pref, preb, l1f_Whh, l1b_Whh, m);

  logits_kernel<<<8192, 256, 0, stream>>>(m, W0, b0, gz0, z);
  softmax_t_kernel<<<64, 512, 0, stream>>>(z, p1);

  gemm_mfma_kernel<<<dim3(256, 4), 256, 0, stream>>>(m, l2f_Wih, l2f_bih, l2f_bhh, pref, 256, 512);
  gemm_mfma_kernel<<<dim3(256, 4), 256, 0, stream>>>(m, l2b_Wih, l2b_bih, l2b_bhh, preb, 256, 512);
  lstm_kernel<<<dim3(64, 2), 512, 0, stream>>>(pref, preb, l2f_Whh, l2b_Whh, m2);

  logits_kernel<<<8192, 256, 0, stream>>>(m2, W1, b1, gz1, z);
  softmax_t_kernel<<<64, 512, 0, stream>>>(z, p2);
}